// Round 1
// baseline (359.472 us; speedup 1.0000x reference)
//
#include <hip/hip_runtime.h>

#define B_ROWS 32768
#define NIN 41
#define NL2 4
#define NRC 8

// clamp via single v_med3_f32
__device__ __forceinline__ float med3(float v, float lo, float hi) {
    return __builtin_amdgcn_fmed3f(v, lo, hi);
}

__device__ __forceinline__ float rl63(float v) {
    return __int_as_float(__builtin_amdgcn_readlane(__float_as_int(v), 63));
}

// ---- fused-DPP batched wave reductions -------------------------------------
// N independent 64-lane sums, one v_add_f32_dpp per step (no mov_dpp+add
// pairs). Chains are interleaved so dependent same-register DPP ops are >=4
// instruction slots apart (covers the GFX9-family "VALU write -> DPP read"
// wait-state requirement inside the block); s_nop 1 at entry/exit guards the
// block boundaries, since the compiler's hazard recognizer cannot see into
// inline asm. bound_ctrl:0 (SP3 spelling) = invalid lanes source 0, matching
// the old update_dpp(0, ..., bound_ctrl=true) semantics.
#define DPP8(C) \
    "v_add_f32_dpp %0, %0, %0 " C " row_mask:0xf bank_mask:0xf bound_ctrl:0\n\t" \
    "v_add_f32_dpp %1, %1, %1 " C " row_mask:0xf bank_mask:0xf bound_ctrl:0\n\t" \
    "v_add_f32_dpp %2, %2, %2 " C " row_mask:0xf bank_mask:0xf bound_ctrl:0\n\t" \
    "v_add_f32_dpp %3, %3, %3 " C " row_mask:0xf bank_mask:0xf bound_ctrl:0\n\t" \
    "v_add_f32_dpp %4, %4, %4 " C " row_mask:0xf bank_mask:0xf bound_ctrl:0\n\t" \
    "v_add_f32_dpp %5, %5, %5 " C " row_mask:0xf bank_mask:0xf bound_ctrl:0\n\t" \
    "v_add_f32_dpp %6, %6, %6 " C " row_mask:0xf bank_mask:0xf bound_ctrl:0\n\t" \
    "v_add_f32_dpp %7, %7, %7 " C " row_mask:0xf bank_mask:0xf bound_ctrl:0\n\t"

__device__ __forceinline__ void wave_sum8(float* v) {
    asm("s_nop 1\n\t"
        DPP8("row_shr:1")
        DPP8("row_shr:2")
        DPP8("row_shr:4")
        DPP8("row_shr:8")
        DPP8("row_bcast:15")
        DPP8("row_bcast:31")
        "s_nop 1"
        : "+v"(v[0]), "+v"(v[1]), "+v"(v[2]), "+v"(v[3]),
          "+v"(v[4]), "+v"(v[5]), "+v"(v[6]), "+v"(v[7]));
}

#define DPP4(C) \
    "v_add_f32_dpp %0, %0, %0 " C " row_mask:0xf bank_mask:0xf bound_ctrl:0\n\t" \
    "v_add_f32_dpp %1, %1, %1 " C " row_mask:0xf bank_mask:0xf bound_ctrl:0\n\t" \
    "v_add_f32_dpp %2, %2, %2 " C " row_mask:0xf bank_mask:0xf bound_ctrl:0\n\t" \
    "v_add_f32_dpp %3, %3, %3 " C " row_mask:0xf bank_mask:0xf bound_ctrl:0\n\t"

__device__ __forceinline__ void wave_sum4(float* v) {
    asm("s_nop 1\n\t"
        DPP4("row_shr:1")
        DPP4("row_shr:2")
        DPP4("row_shr:4")
        DPP4("row_shr:8")
        DPP4("row_bcast:15")
        DPP4("row_bcast:31")
        "s_nop 1"
        : "+v"(v[0]), "+v"(v[1]), "+v"(v[2]), "+v"(v[3]));
}

__device__ __forceinline__ void blur8(float* v) {
    float t[NRC];
    #pragma unroll
    for (int r = 0; r < NRC; ++r) {
        float s = 0.8f * v[r];
        if (r > 0)       s += 0.1f * v[r - 1];
        if (r < NRC - 1) s += 0.1f * v[r + 1];
        t[r] = s;
    }
    #pragma unroll
    for (int r = 0; r < NRC; ++r) v[r] = t[r];
}

__device__ __forceinline__ void blur4(float* v) {
    float t[NL2];
    #pragma unroll
    for (int o = 0; o < NL2; ++o) {
        float s = 0.8f * v[o];
        if (o > 0)       s += 0.1f * v[o - 1];
        if (o < NL2 - 1) s += 0.1f * v[o + 1];
        t[o] = s;
    }
    #pragma unroll
    for (int o = 0; o < NL2; ++o) v[o] = t[o];
}

__global__ void __launch_bounds__(256, 4) pgnet_kernel(
    const float* __restrict__ inp,
    const float* __restrict__ fpg_w,
    const float* __restrict__ fpg_b,
    const float* __restrict__ rpg_w,
    const float* __restrict__ rpg_b,
    const float* __restrict__ pgw,   // [8,86]
    const float* __restrict__ pgb,   // [8]
    float* __restrict__ out)
{
    const int lane = threadIdx.x & 63;
    const int row  = blockIdx.x * 4 + (threadIdx.x >> 6);
    const bool act = lane < NIN;
    const int safe = act ? lane : (NIN - 1);   // in-bounds address for all lanes

    // ======== load issue ordered by FIRST USE, so vmcnt waits are =========
    // ======== incremental instead of a full pre-math drain        =========

    // group 1: pgctrl table + input + biases (feed A[r] / early math)
    float w1r[NRC], w2r[NRC];
    #pragma unroll
    for (int r = 0; r < NRC; ++r) {
        w1r[r] = pgw[r * 86 + safe];
        w2r[r] = pgw[r * 86 + 45 + safe];
    }
    const float x_raw = inp[row * NIN + safe];
    const float4 fbv  = *(const float4*)(fpg_b + (size_t)row * NL2); // wave-uniform
    const float  rb_r = rpg_b[row * NIN + safe];
    __builtin_amdgcn_sched_barrier(0);

    // group 2: fpg_w[b,o,i,r]: b*1312 + o*328 + i*8 + r (first used mid-iter1)
    const float* fp = fpg_w + (size_t)row * 1312 + (size_t)safe * 8;
    float4 fwv[NL2][2];
    #pragma unroll
    for (int o = 0; o < NL2; ++o) {
        fwv[o][0] = *(const float4*)(fp + o * 328);
        fwv[o][1] = *(const float4*)(fp + o * 328 + 4);
    }
    __builtin_amdgcn_sched_barrier(0);

    // group 3: rpg_w[b,i,o,r]: b*1312 + i*32 + o*8 + r (first used late-iter1)
    const float* rp = rpg_w + (size_t)row * 1312 + (size_t)safe * 32;
    float4 rwv[8];
    #pragma unroll
    for (int j = 0; j < 8; ++j) rwv[j] = ((const float4*)rp)[j];
    __builtin_amdgcn_sched_barrier(0);   // pin: all loads issued before math
    // ======================================================================

    const float x  = act ? x_raw : 0.0f;
    const float rb = act ? rb_r  : 0.0f;

    // A[r] = pgb[r] + sum_i x_i*(W[r,i]+W[r,45+i])
    // needs only group 1 -> runs while 16 weight dwordx4 loads are in flight
    float t8[NRC];
    #pragma unroll
    for (int r = 0; r < NRC; ++r) t8[r] = x * (w1r[r] + w2r[r]);
    wave_sum8(t8);
    float A[NRC], W2[NRC];
    #pragma unroll
    for (int r = 0; r < NRC; ++r) {
        A[r]  = rl63(t8[r]) + pgb[r];
        W2[r] = act ? w2r[r] : 0.0f;
    }

    const float fb[NL2] = {fbv.x, fbv.y, fbv.z, fbv.w};

    float l1, rcv[NRC], l2v[NL2];

    // ---------------- iteration 1 (l1i == 0 -> no corr) ----------------
    #pragma unroll
    for (int r = 0; r < NRC; ++r) {
        const float pre = A[r];
        const float v = (pre >= 0.f) ? pre : 0.2f * pre;
        rcv[r] = med3(0.4f * v, -0.2f, 1.0f);
    }
    blur8(rcv); blur8(rcv); blur8(rcv);

    // clamp fpg weights here: first wait on group 2 (group 3 still in flight)
    float fw[NL2][NRC];
    #pragma unroll
    for (int o = 0; o < NL2; ++o) {
        fw[o][0] = med3(fwv[o][0].x, -1.f, 1.f); fw[o][1] = med3(fwv[o][0].y, -1.f, 1.f);
        fw[o][2] = med3(fwv[o][0].z, -1.f, 1.f); fw[o][3] = med3(fwv[o][0].w, -1.f, 1.f);
        fw[o][4] = med3(fwv[o][1].x, -1.f, 1.f); fw[o][5] = med3(fwv[o][1].y, -1.f, 1.f);
        fw[o][6] = med3(fwv[o][1].z, -1.f, 1.f); fw[o][7] = med3(fwv[o][1].w, -1.f, 1.f);
    }

    // l2_pre[o] = sum_i x_i * (sum_r fw[o,i,r]*rc[r])
    float t4[NL2];
    #pragma unroll
    for (int o = 0; o < NL2; ++o) {
        float d = 0.f;
        #pragma unroll
        for (int r = 0; r < NRC; ++r) d += fw[o][r] * rcv[r];
        t4[o] = x * d;
    }
    wave_sum4(t4);
    #pragma unroll
    for (int o = 0; o < NL2; ++o)
        l2v[o] = med3(0.1f * (rl63(t4[o]) + fb[o]), -0.2f, 1.0f);
    blur4(l2v); blur4(l2v);

    // clamp rpg weights here: first wait on group 3 (had ~whole iter1 to land)
    float rw[NL2][NRC];
    #pragma unroll
    for (int o = 0; o < NL2; ++o) {
        rw[o][0] = med3(rwv[2*o].x, -1.f, 1.f);   rw[o][1] = med3(rwv[2*o].y, -1.f, 1.f);
        rw[o][2] = med3(rwv[2*o].z, -1.f, 1.f);   rw[o][3] = med3(rwv[2*o].w, -1.f, 1.f);
        rw[o][4] = med3(rwv[2*o+1].x, -1.f, 1.f); rw[o][5] = med3(rwv[2*o+1].y, -1.f, 1.f);
        rw[o][6] = med3(rwv[2*o+1].z, -1.f, 1.f); rw[o][7] = med3(rwv[2*o+1].w, -1.f, 1.f);
    }

    {
        float acc = rb;
        #pragma unroll
        for (int o = 0; o < NL2; ++o) {
            float d = 0.f;
            #pragma unroll
            for (int r = 0; r < NRC; ++r) d += rw[o][r] * rcv[r];
            acc += l2v[o] * d;
        }
        l1 = med3(acc, -0.2f, 1.0f);
    }

    // ---------------- iteration 2 ----------------
    #pragma unroll
    for (int r = 0; r < NRC; ++r) t8[r] = l1 * W2[r];
    wave_sum8(t8);
    #pragma unroll
    for (int r = 0; r < NRC; ++r) {
        const float pre = A[r] - rl63(t8[r]);
        const float v = (pre >= 0.f) ? pre : 0.2f * pre;
        rcv[r] = med3(0.4f * v, -0.2f, 1.0f);
    }
    blur8(rcv); blur8(rcv); blur8(rcv);

    #pragma unroll
    for (int o = 0; o < NL2; ++o) {
        float d = 0.f;
        #pragma unroll
        for (int r = 0; r < NRC; ++r) d += fw[o][r] * rcv[r];
        t4[o] = x * d;
    }
    wave_sum4(t4);
    #pragma unroll
    for (int o = 0; o < NL2; ++o)
        l2v[o] = med3(0.1f * (rl63(t4[o]) + fb[o]), -0.2f, 1.0f);
    blur4(l2v); blur4(l2v);

    {
        float acc = rb;
        #pragma unroll
        for (int o = 0; o < NL2; ++o) {
            float d = 0.f;
            #pragma unroll
            for (int r = 0; r < NRC; ++r) d += rw[o][r] * rcv[r];
            acc += l2v[o] * d;
        }
        l1 = med3(acc, -0.2f, 1.0f);
    }

    // ---------- stores: [l1i (B*41) | l2 (B*4) | rc (B*8)] ----------
    if (act) out[(size_t)row * NIN + lane] = l1;
    if (lane < NL2) {
        float v = l2v[0];
        #pragma unroll
        for (int o = 1; o < NL2; ++o) if (lane == o) v = l2v[o];
        out[(size_t)B_ROWS * NIN + (size_t)row * NL2 + lane] = v;
    }
    if (lane < NRC) {
        float v = rcv[0];
        #pragma unroll
        for (int r = 1; r < NRC; ++r) if (lane == r) v = rcv[r];
        out[(size_t)B_ROWS * (NIN + NL2) + (size_t)row * NRC + lane] = v;
    }
}

extern "C" void kernel_launch(void* const* d_in, const int* in_sizes, int n_in,
                              void* d_out, int out_size, void* d_ws, size_t ws_size,
                              hipStream_t stream) {
    const float* inp   = (const float*)d_in[0];
    const float* fpg_w = (const float*)d_in[1];
    const float* fpg_b = (const float*)d_in[2];
    const float* rpg_w = (const float*)d_in[3];
    const float* rpg_b = (const float*)d_in[4];
    const float* pgw   = (const float*)d_in[5];
    const float* pgb   = (const float*)d_in[6];
    float* out = (float*)d_out;

    dim3 grid(B_ROWS / 4);   // one wave per row
    dim3 block(256);
    hipLaunchKernelGGL(pgnet_kernel, grid, block, 0, stream,
                       inp, fpg_w, fpg_b, rpg_w, rpg_b, pgw, pgb, out);
}